// Round 6
// baseline (376.371 us; speedup 1.0000x reference)
//
#include <hip/hip_runtime.h>
#include <hip/hip_bf16.h>
#include <hip/hip_fp16.h>
#include <stdint.h>

#define N_NODES 100000
#define IN_CH   128
#define HID     128
#define OUT_CH  64
#define N_EDGES 1600000

#define NB    196      // buckets of 512 nodes
#define NBLK  250      // edge-partition blocks for phases A/B
#define EPB   6400     // edges per block

typedef __attribute__((ext_vector_type(8))) short  s16x8;   // 8 f16 lanes for MFMA
typedef __attribute__((ext_vector_type(4))) float  f32x4;

union U4 { uint4 u; __half2 h[4]; unsigned int w[4]; };

// ---------------- CSR build: bucket sort (as R5) ----------------

__global__ __launch_bounds__(256) void k_phaseA(const int* __restrict__ dst,
                                                int* __restrict__ Cm) {
    __shared__ int hist[NB];
    int blk = blockIdx.x, t = threadIdx.x;
    if (t < NB) hist[t] = 0;
    __syncthreads();
    int base = blk * EPB;
#pragma unroll 5
    for (int k = 0; k < EPB / 256; k++) {
        int d = dst[base + k * 256 + t];
        atomicAdd(&hist[d >> 9], 1);
    }
    __syncthreads();
    if (t < NB) Cm[blk * NB + t] = hist[t];
}

__global__ __launch_bounds__(256) void k_scanBkt(int* __restrict__ Cm,
                                                 int* __restrict__ bktSum) {
    __shared__ int sdata[256];
    int b = blockIdx.x, t = threadIdx.x;
    int v = (t < NBLK) ? Cm[t * NB + b] : 0;
    sdata[t] = v;
    __syncthreads();
    int val = v;
    for (int off = 1; off < 256; off <<= 1) {
        int tmp = (t >= off) ? sdata[t - off] : 0;
        __syncthreads();
        val += tmp;
        sdata[t] = val;
        __syncthreads();
    }
    if (t < NBLK) Cm[t * NB + b] = val - v;
    if (t == 255) bktSum[b] = val;
}

__global__ __launch_bounds__(256) void k_scanBase(const int* __restrict__ bktSum,
                                                  int* __restrict__ bktBase) {
    __shared__ int sdata[256];
    int t = threadIdx.x;
    int v = (t < NB) ? bktSum[t] : 0;
    sdata[t] = v;
    __syncthreads();
    int val = v;
    for (int off = 1; off < 256; off <<= 1) {
        int tmp = (t >= off) ? sdata[t - off] : 0;
        __syncthreads();
        val += tmp;
        sdata[t] = val;
        __syncthreads();
    }
    if (t < NB) bktBase[t] = val - v;
    if (t == 0) bktBase[NB] = N_EDGES;
}

__global__ __launch_bounds__(256) void k_phaseB(const int* __restrict__ src,
                                                const int* __restrict__ dst,
                                                const int* __restrict__ Cm,
                                                const int* __restrict__ bktBase,
                                                unsigned int* __restrict__ bucketed) {
    __shared__ int offs[NB];
    int blk = blockIdx.x, t = threadIdx.x;
    if (t < NB) offs[t] = Cm[blk * NB + t] + bktBase[t];
    __syncthreads();
    int base = blk * EPB;
#pragma unroll 5
    for (int k = 0; k < EPB / 256; k++) {
        int e = base + k * 256 + t;
        int d = dst[e];
        int sv = src[e];
        int pos = atomicAdd(&offs[d >> 9], 1);
        bucketed[pos] = ((unsigned int)sv << 9) | (unsigned int)(d & 511);
    }
}

__global__ __launch_bounds__(512) void k_phaseC(const unsigned int* __restrict__ bucketed,
                                                const int* __restrict__ bktBase,
                                                int* __restrict__ rowptr,
                                                float* __restrict__ dinvg,
                                                int* __restrict__ csr_src) {
    __shared__ int cnt[512];
    __shared__ int cur[512];
    __shared__ int sdata[512];
    int b = blockIdx.x, t = threadIdx.x;
    int base = bktBase[b], endR = bktBase[b + 1];
    int nodeBase = b << 9;
    int nNodes = N_NODES - nodeBase;
    if (nNodes > 512) nNodes = 512;

    cnt[t] = 0;
    __syncthreads();
    for (int e = base + t; e < endR; e += 512)
        atomicAdd(&cnt[bucketed[e] & 511], 1);
    __syncthreads();

    int s = cnt[t];
    sdata[t] = s;
    __syncthreads();
    int val = s;
    for (int off = 1; off < 512; off <<= 1) {
        int tmp = (t >= off) ? sdata[t - off] : 0;
        __syncthreads();
        val += tmp;
        sdata[t] = val;
        __syncthreads();
    }
    cur[t] = val - s;
    if (t < nNodes) {
        rowptr[nodeBase + t] = base + val - s;
        dinvg[nodeBase + t] = rsqrtf((float)s + 1.0f);
    }
    if (b == NB - 1 && t == 0) rowptr[N_NODES] = N_EDGES;
    __syncthreads();

    for (int e = base + t; e < endR; e += 512) {
        unsigned int u = bucketed[e];
        int pos = base + atomicAdd(&cur[u & 511], 1);
        csr_src[pos] = (int)(u >> 9);
    }
}

// ---------------- W prep: transpose to f16 [n][k], fuse mu|ls concat --------

__global__ __launch_bounds__(256) void k_prepW(const float* __restrict__ W1,
                                               const float* __restrict__ Wmu,
                                               const float* __restrict__ Wls,
                                               unsigned short* __restrict__ Wt1,
                                               unsigned short* __restrict__ WtC) {
    int idx = blockIdx.x * 256 + threadIdx.x;
    int n = idx >> 7, k = idx & 127;
    __half a = __float2half(W1[k * 128 + n]);
    __half b = __float2half((n < 64) ? Wmu[k * 64 + n] : Wls[k * 64 + (n - 64)]);
    Wt1[idx] = *(unsigned short*)&a;
    WtC[idx] = *(unsigned short*)&b;
}

// ---------------- MFMA GEMM1: x[f32] @ W1 -> h0[f16] -----------------------

#define LDA 136

__global__ __launch_bounds__(256) void k_gemm1(const float* __restrict__ X,
                                               const unsigned short* __restrict__ Wt,
                                               unsigned short* __restrict__ Y) {
    __shared__ unsigned short sA[128 * LDA];
    int t = threadIdx.x;
    int R0 = blockIdx.x * 128;
    int row = t >> 1, colb = (t & 1) * 64;
    bool valid = (R0 + row) < N_NODES;
    const float* Xr = X + (size_t)(R0 + row) * 128 + colb;
    unsigned short* dp = sA + row * LDA + colb;
#pragma unroll
    for (int j = 0; j < 16; j++) {
        float4 v = valid ? *(const float4*)(Xr + j * 4) : make_float4(0.f, 0.f, 0.f, 0.f);
        __half2 p0 = __floats2half2_rn(v.x, v.y);
        __half2 p1 = __floats2half2_rn(v.z, v.w);
        uint2 o;
        o.x = *(unsigned int*)&p0;
        o.y = *(unsigned int*)&p1;
        *(uint2*)(dp + j * 4) = o;
    }
    __syncthreads();

    int wv = t >> 6, l = t & 63;
    int quad = l >> 4, lm = l & 15;

    s16x8 a[2][4];
#pragma unroll
    for (int mt = 0; mt < 2; mt++)
#pragma unroll
        for (int ks = 0; ks < 4; ks++)
            a[mt][ks] = *(const s16x8*)(sA + (wv * 32 + mt * 16 + lm) * LDA +
                                        ks * 32 + quad * 8);

    f32x4 acc[2][8] = {};
#pragma unroll
    for (int nt = 0; nt < 8; nt++) {
        s16x8 b[4];
        const unsigned short* Wp = Wt + (nt * 16 + lm) * 128 + quad * 8;
#pragma unroll
        for (int ks = 0; ks < 4; ks++)
            b[ks] = *(const s16x8*)(Wp + ks * 32);
#pragma unroll
        for (int mt = 0; mt < 2; mt++) {
            f32x4 c = acc[mt][nt];
#pragma unroll
            for (int ks = 0; ks < 4; ks++)
                c = __builtin_amdgcn_mfma_f32_16x16x32_f16(a[mt][ks], b[ks], c, 0, 0, 0);
            acc[mt][nt] = c;
        }
    }

    int rbase = R0 + wv * 32 + quad * 4;
#pragma unroll
    for (int mt = 0; mt < 2; mt++)
#pragma unroll
        for (int nt = 0; nt < 8; nt++)
#pragma unroll
            for (int reg = 0; reg < 4; reg++) {
                int r = rbase + mt * 16 + reg;
                if (r < N_NODES) {
                    __half hv = __float2half(acc[mt][nt][reg]);
                    Y[(size_t)r * 128 + nt * 16 + lm] = *(unsigned short*)&hv;
                }
            }
}

// ------- agg gather core: wave = 1 node, 16 lanes/row (dwordx4), f16 -------
// group g = lane>>4 handles edges p+j*4+g; lane holds 8 channels (lm*8..+7).
// acc in packed f16 (__hfma2); cross-group combine via 2 shfl_xor rounds.

#define AGG_GATHER(tbl)                                                        \
    int l = threadIdx.x & 63;                                                  \
    int wv = threadIdx.x >> 6;                                                 \
    int i = __builtin_amdgcn_readfirstlane(blockIdx.x * 4 + wv);               \
    int g = l >> 4, lm = l & 15;                                               \
    float di = dinv[i];                                                        \
    U4 rs; rs.u = *(const uint4*)((tbl) + (size_t)i * 128 + lm * 8);           \
    float ns = (g == 0) ? di * di : 0.f;                                       \
    __half2 ns2 = __floats2half2_rn(ns, ns);                                   \
    __half2 acc0 = __hmul2(rs.h[0], ns2);                                      \
    __half2 acc1 = __hmul2(rs.h[1], ns2);                                      \
    __half2 acc2 = __hmul2(rs.h[2], ns2);                                      \
    __half2 acc3 = __hmul2(rs.h[3], ns2);                                      \
    int beg = rowptr[i], end = rowptr[i + 1];                                  \
    for (int p = beg; p < end; p += 16) {                                      \
        int s[4]; float n[4]; U4 r[4];                                         \
        _Pragma("unroll")                                                      \
        for (int j = 0; j < 4; j++) {                                          \
            int q = p + j * 4 + g;                                             \
            s[j] = csr_src[q < end ? q : end - 1];                             \
        }                                                                      \
        _Pragma("unroll")                                                      \
        for (int j = 0; j < 4; j++) n[j] = dinv[s[j]];                         \
        _Pragma("unroll")                                                      \
        for (int j = 0; j < 4; j++)                                            \
            r[j].u = *(const uint4*)((tbl) + (size_t)s[j] * 128 + lm * 8);     \
        _Pragma("unroll")                                                      \
        for (int j = 0; j < 4; j++) {                                          \
            float nn = (p + j * 4 + g < end) ? n[j] * di : 0.f;                \
            __half2 nh = __floats2half2_rn(nn, nn);                            \
            acc0 = __hfma2(r[j].h[0], nh, acc0);                               \
            acc1 = __hfma2(r[j].h[1], nh, acc1);                               \
            acc2 = __hfma2(r[j].h[2], nh, acc2);                               \
            acc3 = __hfma2(r[j].h[3], nh, acc3);                               \
        }                                                                      \
    }                                                                          \
    /* combine groups: lanes ^16 then ^32 */                                   \
    {                                                                          \
        int v0 = *(int*)&acc0, v1 = *(int*)&acc1,                              \
            v2 = *(int*)&acc2, v3 = *(int*)&acc3;                              \
        int u0 = __shfl_xor(v0, 16), u1 = __shfl_xor(v1, 16),                  \
            u2 = __shfl_xor(v2, 16), u3 = __shfl_xor(v3, 16);                  \
        acc0 = __hadd2(acc0, *(__half2*)&u0);                                  \
        acc1 = __hadd2(acc1, *(__half2*)&u1);                                  \
        acc2 = __hadd2(acc2, *(__half2*)&u2);                                  \
        acc3 = __hadd2(acc3, *(__half2*)&u3);                                  \
        v0 = *(int*)&acc0; v1 = *(int*)&acc1;                                  \
        v2 = *(int*)&acc2; v3 = *(int*)&acc3;                                  \
        u0 = __shfl_xor(v0, 32); u1 = __shfl_xor(v1, 32);                      \
        u2 = __shfl_xor(v2, 32); u3 = __shfl_xor(v3, 32);                      \
        acc0 = __hadd2(acc0, *(__half2*)&u0);                                  \
        acc1 = __hadd2(acc1, *(__half2*)&u1);                                  \
        acc2 = __hadd2(acc2, *(__half2*)&u2);                                  \
        acc3 = __hadd2(acc3, *(__half2*)&u3);                                  \
    }

// agg1: h = relu(agg(h0)+b1) -> f16
__global__ __launch_bounds__(256) void k_agg1(const unsigned short* __restrict__ h0,
                                              const int* __restrict__ rowptr,
                                              const int* __restrict__ csr_src,
                                              const float* __restrict__ dinv,
                                              const float* __restrict__ b1,
                                              unsigned short* __restrict__ hb) {
    AGG_GATHER(h0)
    if (l < 16) {
        int cb = lm * 8;
        float4 bA = *(const float4*)(b1 + cb);
        float4 bB = *(const float4*)(b1 + cb + 4);
        float2 f0 = __half22float2(acc0), f1 = __half22float2(acc1);
        float2 f2 = __half22float2(acc2), f3 = __half22float2(acc3);
        f0.x += bA.x; f0.y += bA.y; f1.x += bA.z; f1.y += bA.w;
        f2.x += bB.x; f2.y += bB.y; f3.x += bB.z; f3.y += bB.w;
        f0.x = f0.x > 0.f ? f0.x : 0.f;  f0.y = f0.y > 0.f ? f0.y : 0.f;
        f1.x = f1.x > 0.f ? f1.x : 0.f;  f1.y = f1.y > 0.f ? f1.y : 0.f;
        f2.x = f2.x > 0.f ? f2.x : 0.f;  f2.y = f2.y > 0.f ? f2.y : 0.f;
        f3.x = f3.x > 0.f ? f3.x : 0.f;  f3.y = f3.y > 0.f ? f3.y : 0.f;
        __half2 o0 = __floats2half2_rn(f0.x, f0.y);
        __half2 o1 = __floats2half2_rn(f1.x, f1.y);
        __half2 o2 = __floats2half2_rn(f2.x, f2.y);
        __half2 o3 = __floats2half2_rn(f3.x, f3.y);
        uint4 w;
        w.x = *(unsigned int*)&o0; w.y = *(unsigned int*)&o1;
        w.z = *(unsigned int*)&o2; w.w = *(unsigned int*)&o3;
        *(uint4*)(hb + (size_t)i * 128 + cb) = w;
    }
}

// fused layer 2: g = agg(hb); out = g @ WtC + bias. 4 nodes/block (1/wave),
// MFMA epilogue over 16 LDS rows (rows 4..15 zero-padded).

#define LDG 136

__global__ __launch_bounds__(256) void k_agg2g(const unsigned short* __restrict__ hb,
                                               const int* __restrict__ rowptr,
                                               const int* __restrict__ csr_src,
                                               const float* __restrict__ dinv,
                                               const unsigned short* __restrict__ WtC,
                                               const float* __restrict__ bmu,
                                               const float* __restrict__ bls,
                                               float* __restrict__ out) {
    __shared__ unsigned short gls[16 * LDG];
    {   // zero pad rows 4..15 (rows 0..3 are written below)
        for (int z = threadIdx.x; z < 12 * LDG; z += 256) gls[4 * LDG + z] = 0;
    }
    AGG_GATHER(hb)
    if (l < 16) {
        uint4 w;
        w.x = *(unsigned int*)&acc0; w.y = *(unsigned int*)&acc1;
        w.z = *(unsigned int*)&acc2; w.w = *(unsigned int*)&acc3;
        *(uint4*)(gls + wv * LDG + lm * 8) = w;
    }
    __syncthreads();

    int quad = l >> 4;   // == g
    s16x8 a[4];
#pragma unroll
    for (int ks = 0; ks < 4; ks++)
        a[ks] = *(const s16x8*)(gls + lm * LDG + ks * 32 + quad * 8);

    int nodeBase = blockIdx.x * 4;
#pragma unroll
    for (int nt2 = 0; nt2 < 2; nt2++) {
        int nt = wv * 2 + nt2;
        f32x4 acc = {};
        const unsigned short* Wp = WtC + (nt * 16 + lm) * 128 + quad * 8;
#pragma unroll
        for (int ks = 0; ks < 4; ks++) {
            s16x8 b = *(const s16x8*)(Wp + ks * 32);
            acc = __builtin_amdgcn_mfma_f32_16x16x32_f16(a[ks], b, acc, 0, 0, 0);
        }
        if (quad == 0) {   // C rows 0..3 = the block's 4 nodes
            int col = nt * 16 + lm;
#pragma unroll
            for (int reg = 0; reg < 4; reg++) {
                int row = nodeBase + reg;
                float v = acc[reg];
                if (col < 64)
                    out[(size_t)row * 64 + col] = v + bmu[col];
                else
                    out[(size_t)N_NODES * 64 + (size_t)row * 64 + (col - 64)] =
                        v + bls[col - 64];
            }
        }
    }
}

// ---------------- launch ----------------

extern "C" void kernel_launch(void* const* d_in, const int* in_sizes, int n_in,
                              void* d_out, int out_size, void* d_ws, size_t ws_size,
                              hipStream_t stream) {
    const float* x    = (const float*)d_in[0];
    const int*   ei   = (const int*)d_in[1];
    const float* W1   = (const float*)d_in[2];
    const float* b1   = (const float*)d_in[3];
    const float* Wmu  = (const float*)d_in[4];
    const float* bmu  = (const float*)d_in[5];
    const float* Wls  = (const float*)d_in[6];
    const float* bls  = (const float*)d_in[7];
    const int* src = ei;
    const int* dst = ei + N_EDGES;

    char* p = (char*)d_ws;
    unsigned short* bufA = (unsigned short*)p; p += (size_t)N_NODES * 128 * 2; // h0 (f16)
    unsigned short* bufH = (unsigned short*)p; p += (size_t)N_NODES * 128 * 2; // h  (f16)
    unsigned short* Wt1  = (unsigned short*)p; p += 128 * 128 * 2;
    unsigned short* WtC  = (unsigned short*)p; p += 128 * 128 * 2;
    int*   Cm      = (int*)p;   p += (size_t)NBLK * NB * 4;
    int*   bktSum  = (int*)p;   p += 256 * 4;
    int*   bktBase = (int*)p;   p += 256 * 4;
    int*   rowptr  = (int*)p;   p += 400016;
    float* dinv    = (float*)p; p += 400000;
    unsigned int* bucketed = (unsigned int*)p; p += (size_t)N_EDGES * 4;
    int*   csr_src = (int*)p;   p += (size_t)N_EDGES * 4;

    // CSR build
    k_phaseA<<<NBLK, 256, 0, stream>>>(dst, Cm);
    k_scanBkt<<<NB, 256, 0, stream>>>(Cm, bktSum);
    k_scanBase<<<1, 256, 0, stream>>>(bktSum, bktBase);
    k_phaseB<<<NBLK, 256, 0, stream>>>(src, dst, Cm, bktBase, bucketed);
    k_phaseC<<<NB, 512, 0, stream>>>(bucketed, bktBase, rowptr, dinv, csr_src);

    k_prepW<<<64, 256, 0, stream>>>(W1, Wmu, Wls, Wt1, WtC);

    int gblk = (N_NODES + 127) / 128;   // 782

    // layer 1: h0 = x @ W1 (MFMA f16) ; h = relu(agg(h0) + b1) (f16)
    k_gemm1<<<gblk, 256, 0, stream>>>(x, Wt1, bufA);
    k_agg1<<<N_NODES / 4, 256, 0, stream>>>(bufA, rowptr, csr_src, dinv, b1, bufH);

    // layer 2 (reordered): out = agg(h) @ [Wmu|Wls] + bias, fused
    k_agg2g<<<N_NODES / 4, 256, 0, stream>>>(bufH, rowptr, csr_src, dinv,
                                             WtC, bmu, bls, (float*)d_out);
}

// Round 7
// 350.630 us; speedup vs baseline: 1.0734x; 1.0734x over previous
//
#include <hip/hip_runtime.h>
#include <hip/hip_bf16.h>
#include <hip/hip_fp16.h>
#include <stdint.h>

#define N_NODES 100000
#define IN_CH   128
#define HID     128
#define OUT_CH  64
#define N_EDGES 1600000

#define NB    196      // buckets of 512 nodes
#define NBLK  250      // edge-partition blocks for phases A/B
#define EPB   6400     // edges per block

typedef __attribute__((ext_vector_type(8))) short  s16x8;   // 8 f16 for MFMA
typedef __attribute__((ext_vector_type(4))) float  f32x4;

__device__ __forceinline__ __half2 as_h2(unsigned int u) { return *(__half2*)&u; }

// ---------------- CSR build: bucket sort ----------------

__global__ __launch_bounds__(256) void k_phaseA(const int* __restrict__ dst,
                                                int* __restrict__ Cm) {
    __shared__ int hist[NB];
    int blk = blockIdx.x, t = threadIdx.x;
    if (t < NB) hist[t] = 0;
    __syncthreads();
    int base = blk * EPB;
#pragma unroll 5
    for (int k = 0; k < EPB / 256; k++) {
        int d = dst[base + k * 256 + t];
        atomicAdd(&hist[d >> 9], 1);
    }
    __syncthreads();
    if (t < NB) Cm[blk * NB + t] = hist[t];
}

__global__ __launch_bounds__(256) void k_scanBkt(int* __restrict__ Cm,
                                                 int* __restrict__ bktSum) {
    __shared__ int sdata[256];
    int b = blockIdx.x, t = threadIdx.x;
    int v = (t < NBLK) ? Cm[t * NB + b] : 0;
    sdata[t] = v;
    __syncthreads();
    int val = v;
    for (int off = 1; off < 256; off <<= 1) {
        int tmp = (t >= off) ? sdata[t - off] : 0;
        __syncthreads();
        val += tmp;
        sdata[t] = val;
        __syncthreads();
    }
    if (t < NBLK) Cm[t * NB + b] = val - v;
    if (t == 255) bktSum[b] = val;
}

__global__ __launch_bounds__(256) void k_scanBase(const int* __restrict__ bktSum,
                                                  int* __restrict__ bktBase) {
    __shared__ int sdata[256];
    int t = threadIdx.x;
    int v = (t < NB) ? bktSum[t] : 0;
    sdata[t] = v;
    __syncthreads();
    int val = v;
    for (int off = 1; off < 256; off <<= 1) {
        int tmp = (t >= off) ? sdata[t - off] : 0;
        __syncthreads();
        val += tmp;
        sdata[t] = val;
        __syncthreads();
    }
    if (t < NB) bktBase[t] = val - v;
    if (t == 0) bktBase[NB] = N_EDGES;
}

__global__ __launch_bounds__(256) void k_phaseB(const int* __restrict__ src,
                                                const int* __restrict__ dst,
                                                const int* __restrict__ Cm,
                                                const int* __restrict__ bktBase,
                                                unsigned int* __restrict__ bucketed) {
    __shared__ int offs[NB];
    int blk = blockIdx.x, t = threadIdx.x;
    if (t < NB) offs[t] = Cm[blk * NB + t] + bktBase[t];
    __syncthreads();
    int base = blk * EPB;
#pragma unroll 5
    for (int k = 0; k < EPB / 256; k++) {
        int e = base + k * 256 + t;
        int d = dst[e];
        int sv = src[e];
        int pos = atomicAdd(&offs[d >> 9], 1);
        bucketed[pos] = ((unsigned int)sv << 9) | (unsigned int)(d & 511);
    }
}

__global__ __launch_bounds__(512) void k_phaseC(const unsigned int* __restrict__ bucketed,
                                                const int* __restrict__ bktBase,
                                                int* __restrict__ rowptr,
                                                float* __restrict__ dinvg,
                                                unsigned int* __restrict__ dinvh2,
                                                int* __restrict__ csr_src) {
    __shared__ int cnt[512];
    __shared__ int cur[512];
    __shared__ int sdata[512];
    int b = blockIdx.x, t = threadIdx.x;
    int base = bktBase[b], endR = bktBase[b + 1];
    int nodeBase = b << 9;
    int nNodes = N_NODES - nodeBase;
    if (nNodes > 512) nNodes = 512;

    cnt[t] = 0;
    __syncthreads();
    for (int e = base + t; e < endR; e += 512)
        atomicAdd(&cnt[bucketed[e] & 511], 1);
    __syncthreads();

    int s = cnt[t];
    sdata[t] = s;
    __syncthreads();
    int val = s;
    for (int off = 1; off < 512; off <<= 1) {
        int tmp = (t >= off) ? sdata[t - off] : 0;
        __syncthreads();
        val += tmp;
        sdata[t] = val;
        __syncthreads();
    }
    cur[t] = val - s;
    if (t < nNodes) {
        rowptr[nodeBase + t] = base + val - s;
        float dv = rsqrtf((float)s + 1.0f);
        dinvg[nodeBase + t] = dv;
        __half hd = __float2half(dv);
        unsigned int hu = *(unsigned short*)&hd;
        dinvh2[nodeBase + t] = hu | (hu << 16);
    }
    if (b == NB - 1 && t == 0) rowptr[N_NODES] = N_EDGES;
    __syncthreads();

    for (int e = base + t; e < endR; e += 512) {
        unsigned int u = bucketed[e];
        int pos = base + atomicAdd(&cur[u & 511], 1);
        csr_src[pos] = (int)(u >> 9);
    }
}

// ---------------- W prep: transpose to f16 [n][k], fuse mu|ls concat --------

__global__ __launch_bounds__(256) void k_prepW(const float* __restrict__ W1,
                                               const float* __restrict__ Wmu,
                                               const float* __restrict__ Wls,
                                               unsigned short* __restrict__ Wt1,
                                               unsigned short* __restrict__ WtC) {
    int idx = blockIdx.x * 256 + threadIdx.x;
    int n = idx >> 7, k = idx & 127;
    __half a = __float2half(W1[k * 128 + n]);
    __half b = __float2half((n < 64) ? Wmu[k * 64 + n] : Wls[k * 64 + (n - 64)]);
    Wt1[idx] = *(unsigned short*)&a;
    WtC[idx] = *(unsigned short*)&b;
}

// ---------------- MFMA GEMMs (f16, K=128), 128-row blocks -------------------

#define LDA 136

__device__ __forceinline__ void gemm_core(const unsigned short* sA,
                                          const unsigned short* __restrict__ Wt,
                                          unsigned short* __restrict__ Y,
                                          int R0, int t) {
    int wv = t >> 6, l = t & 63;
    int quad = l >> 4, lm = l & 15;

    s16x8 a[2][4];
#pragma unroll
    for (int mt = 0; mt < 2; mt++)
#pragma unroll
        for (int ks = 0; ks < 4; ks++)
            a[mt][ks] = *(const s16x8*)(sA + (wv * 32 + mt * 16 + lm) * LDA +
                                        ks * 32 + quad * 8);

    f32x4 acc[2][8] = {};
#pragma unroll
    for (int nt = 0; nt < 8; nt++) {
        s16x8 b[4];
        const unsigned short* Wp = Wt + (nt * 16 + lm) * 128 + quad * 8;
#pragma unroll
        for (int ks = 0; ks < 4; ks++)
            b[ks] = *(const s16x8*)(Wp + ks * 32);
#pragma unroll
        for (int mt = 0; mt < 2; mt++) {
            f32x4 c = acc[mt][nt];
#pragma unroll
            for (int ks = 0; ks < 4; ks++)
                c = __builtin_amdgcn_mfma_f32_16x16x32_f16(a[mt][ks], b[ks], c, 0, 0, 0);
            acc[mt][nt] = c;
        }
    }

    int rbase = R0 + wv * 32 + quad * 4;
#pragma unroll
    for (int mt = 0; mt < 2; mt++)
#pragma unroll
        for (int nt = 0; nt < 8; nt++)
#pragma unroll
            for (int reg = 0; reg < 4; reg++) {
                int r = rbase + mt * 16 + reg;
                if (r < N_NODES) {
                    __half hv = __float2half(acc[mt][nt][reg]);
                    Y[(size_t)r * 128 + nt * 16 + lm] = *(unsigned short*)&hv;
                }
            }
}

__global__ __launch_bounds__(256) void k_gemm1(const float* __restrict__ X,
                                               const unsigned short* __restrict__ Wt,
                                               unsigned short* __restrict__ Y) {
    __shared__ unsigned short sA[128 * LDA];
    int t = threadIdx.x;
    int R0 = blockIdx.x * 128;
    int row = t >> 1, colb = (t & 1) * 64;
    bool valid = (R0 + row) < N_NODES;
    const float* Xr = X + (size_t)(R0 + row) * 128 + colb;
    unsigned short* dp = sA + row * LDA + colb;
#pragma unroll
    for (int j = 0; j < 16; j++) {
        float4 v = valid ? *(const float4*)(Xr + j * 4) : make_float4(0.f, 0.f, 0.f, 0.f);
        __half2 p0 = __floats2half2_rn(v.x, v.y);
        __half2 p1 = __floats2half2_rn(v.z, v.w);
        uint2 o;
        o.x = *(unsigned int*)&p0;
        o.y = *(unsigned int*)&p1;
        *(uint2*)(dp + j * 4) = o;
    }
    __syncthreads();
    gemm_core(sA, Wt, Y, R0, t);
}

__global__ __launch_bounds__(256) void k_gemm2(const unsigned short* __restrict__ Xh,
                                               const unsigned short* __restrict__ Wt,
                                               unsigned short* __restrict__ Y) {
    __shared__ unsigned short sA[128 * LDA];
    int t = threadIdx.x;
    int R0 = blockIdx.x * 128;
    int row = t >> 1, colb = (t & 1) * 64;
    bool valid = (R0 + row) < N_NODES;
    const unsigned short* Xr = Xh + (size_t)(R0 + row) * 128 + colb;
    unsigned short* dp = sA + row * LDA + colb;
#pragma unroll
    for (int j = 0; j < 8; j++) {
        uint4 v = valid ? *(const uint4*)(Xr + j * 8) : make_uint4(0u, 0u, 0u, 0u);
        *(uint4*)(dp + j * 8) = v;
    }
    __syncthreads();
    gemm_core(sA, Wt, Y, R0, t);
}

// ---- agg gather core: wave = 1 node, 2 ch/lane, dword gathers, unroll 8 ----
// agg = di * Sum(dinv_s * h_s) + di^2 * h_i  (di hoisted out of the loop).
// Accumulate in packed f16 (hfma2); dinv table pre-packed as half2.

__device__ __forceinline__ float2 agg_gather(const unsigned short* __restrict__ tbl,
                                             const int* __restrict__ rowptr,
                                             const int* __restrict__ csr_src,
                                             const unsigned int* __restrict__ dh2,
                                             const float* __restrict__ dinv,
                                             int i, int c2, float* di_out) {
    float di = dinv[i];
    *di_out = di;
    unsigned int sv = *(const unsigned int*)(tbl + (size_t)i * 128 + c2);
    __half2 acc = __floats2half2_rn(0.f, 0.f);
    int beg = rowptr[i], end = rowptr[i + 1];
    for (int p = beg; p < end; p += 8) {
        int s[8]; unsigned int nv[8]; unsigned int r[8];
#pragma unroll
        for (int j = 0; j < 8; j++) {
            int q = p + j;
            s[j] = csr_src[q < end ? q : end - 1];
        }
#pragma unroll
        for (int j = 0; j < 8; j++) nv[j] = dh2[s[j]];
#pragma unroll
        for (int j = 0; j < 8; j++)
            r[j] = *(const unsigned int*)(tbl + (size_t)s[j] * 128 + c2);
#pragma unroll
        for (int j = 0; j < 8; j++) {
            unsigned int nn = (p + j < end) ? nv[j] : 0u;
            acc = __hfma2(as_h2(r[j]), as_h2(nn), acc);
        }
    }
    float2 f = __half22float2(acc);
    float2 hs = __half22float2(as_h2(sv));
    f.x = di * f.x + di * di * hs.x;
    f.y = di * f.y + di * di * hs.y;
    return f;
}

// agg1: h = relu(agg(h0)+b1) -> f16
__global__ __launch_bounds__(256) void k_agg1(const unsigned short* __restrict__ h0,
                                              const int* __restrict__ rowptr,
                                              const int* __restrict__ csr_src,
                                              const unsigned int* __restrict__ dh2,
                                              const float* __restrict__ dinv,
                                              const float* __restrict__ b1,
                                              unsigned short* __restrict__ hb) {
    int lane = threadIdx.x & 63;
    int i = __builtin_amdgcn_readfirstlane(blockIdx.x * 4 + (threadIdx.x >> 6));
    int c2 = lane * 2;
    float di;
    float2 f = agg_gather(h0, rowptr, csr_src, dh2, dinv, i, c2, &di);
    f.x += b1[c2];
    f.y += b1[c2 + 1];
    f.x = f.x > 0.f ? f.x : 0.f;
    f.y = f.y > 0.f ? f.y : 0.f;
    __half2 o = __floats2half2_rn(f.x, f.y);
    *(unsigned int*)(hb + (size_t)i * 128 + c2) = *(unsigned int*)&o;
}

// agg2: out = agg(t) + bias (f32 out, split mu|logstd)
__global__ __launch_bounds__(256) void k_agg2(const unsigned short* __restrict__ tt,
                                              const int* __restrict__ rowptr,
                                              const int* __restrict__ csr_src,
                                              const unsigned int* __restrict__ dh2,
                                              const float* __restrict__ dinv,
                                              const float* __restrict__ bmu,
                                              const float* __restrict__ bls,
                                              float* __restrict__ out) {
    int lane = threadIdx.x & 63;
    int i = __builtin_amdgcn_readfirstlane(blockIdx.x * 4 + (threadIdx.x >> 6));
    int c2 = lane * 2;
    float di;
    float2 f = agg_gather(tt, rowptr, csr_src, dh2, dinv, i, c2, &di);
    if (lane < 32) {
        int c = c2;                       // mu channels 0..63
        *(float2*)(out + (size_t)i * 64 + c) =
            make_float2(f.x + bmu[c], f.y + bmu[c + 1]);
    } else {
        int c = c2 - 64;                  // logstd channels 0..63
        *(float2*)(out + (size_t)N_NODES * 64 + (size_t)i * 64 + c) =
            make_float2(f.x + bls[c], f.y + bls[c + 1]);
    }
}

// ---------------- launch ----------------

extern "C" void kernel_launch(void* const* d_in, const int* in_sizes, int n_in,
                              void* d_out, int out_size, void* d_ws, size_t ws_size,
                              hipStream_t stream) {
    const float* x    = (const float*)d_in[0];
    const int*   ei   = (const int*)d_in[1];
    const float* W1   = (const float*)d_in[2];
    const float* b1   = (const float*)d_in[3];
    const float* Wmu  = (const float*)d_in[4];
    const float* bmu  = (const float*)d_in[5];
    const float* Wls  = (const float*)d_in[6];
    const float* bls  = (const float*)d_in[7];
    const int* src = ei;
    const int* dst = ei + N_EDGES;

    char* p = (char*)d_ws;
    unsigned short* bufA = (unsigned short*)p; p += (size_t)N_NODES * 128 * 2; // h0, then t (f16)
    unsigned short* bufH = (unsigned short*)p; p += (size_t)N_NODES * 128 * 2; // h (f16)
    unsigned short* Wt1  = (unsigned short*)p; p += 128 * 128 * 2;
    unsigned short* WtC  = (unsigned short*)p; p += 128 * 128 * 2;
    int*   Cm      = (int*)p;   p += (size_t)NBLK * NB * 4;
    int*   bktSum  = (int*)p;   p += 256 * 4;
    int*   bktBase = (int*)p;   p += 256 * 4;
    int*   rowptr  = (int*)p;   p += 400016;
    float* dinv    = (float*)p; p += 400000;
    unsigned int* dinvh2 = (unsigned int*)p; p += 400000;
    unsigned int* bucketed = (unsigned int*)p; p += (size_t)N_EDGES * 4;
    int*   csr_src = (int*)p;   p += (size_t)N_EDGES * 4;

    // CSR build
    k_phaseA<<<NBLK, 256, 0, stream>>>(dst, Cm);
    k_scanBkt<<<NB, 256, 0, stream>>>(Cm, bktSum);
    k_scanBase<<<1, 256, 0, stream>>>(bktSum, bktBase);
    k_phaseB<<<NBLK, 256, 0, stream>>>(src, dst, Cm, bktBase, bucketed);
    k_phaseC<<<NB, 512, 0, stream>>>(bucketed, bktBase, rowptr, dinv, dinvh2, csr_src);

    k_prepW<<<64, 256, 0, stream>>>(W1, Wmu, Wls, Wt1, WtC);

    int gblk = (N_NODES + 127) / 128;   // 782

    // layer 1: h0 = x @ W1 (MFMA f16) ; h = relu(agg(h0) + b1)
    k_gemm1<<<gblk, 256, 0, stream>>>(x, Wt1, bufA);
    k_agg1<<<N_NODES / 4, 256, 0, stream>>>(bufA, rowptr, csr_src, dinvh2, dinv, b1, bufH);

    // layer 2: t = h @ [Wmu|Wls] ; out = agg(t) + bias
    k_gemm2<<<gblk, 256, 0, stream>>>(bufH, WtC, bufA);
    k_agg2<<<N_NODES / 4, 256, 0, stream>>>(bufA, rowptr, csr_src, dinvh2, dinv,
                                            bmu, bls, (float*)d_out);
}